// Round 1
// baseline (136.371 us; speedup 1.0000x reference)
//
#include <hip/hip_runtime.h>

#define FEATS 64
#define PSZ   64            // nodes per partition (= one gather block)
#define MAXP  1280          // >= ceil(75000/64) = 1172
#define PSCH  2344          // edges per chunk; 2344*512 >= 1.2M
#define SPT   512           // prep_scatter threads per block
#define PEPT  5             // ceil(PSCH/SPT)
#define NBMAX 512           // sort blocks = runs per partition
#define CAPP  2560          // padded LDS bucket capacity (mean ~1250, >30 sigma)

typedef __attribute__((ext_vector_type(8))) short short8;   // 8 bf16 = 4 VGPRs
typedef __attribute__((ext_vector_type(4))) float floatx4;  // MFMA accumulator

static __device__ __forceinline__ unsigned short f2bf(float f) {
    const unsigned int u = __float_as_uint(f);
    return (unsigned short)((u + 0x7FFFu + ((u >> 16) & 1u)) >> 16);
}
static __device__ __forceinline__ float bflo(unsigned int u) {
    return __uint_as_float(u << 16);            // low bf16 -> fp32
}
static __device__ __forceinline__ float bfhi(unsigned int u) {
    return __uint_as_float(u & 0xFFFF0000u);    // high bf16 -> fp32
}

// ---------------------------------------------------------------------------
// K1 prep_scatter: (A) vectorized Fs16 = bf16(feature * rsqrt(deg)) — 8 elems
//  per thread (2x float4 load, 1 rsqrt, 1x16B store); (B) LDS partition-sort
//  of a PSCH-edge chunk. Scan is wave-shuffle + cross-wave prefix: 2 barriers
//  instead of 18. Record = src | dl<<17 ; prk = p | r<<11 | dl<<23.
// ---------------------------------------------------------------------------
__global__ __launch_bounds__(SPT) void prep_scatter(
        const float* __restrict__ degree,
        const float* __restrict__ feature,
        const float* __restrict__ Wm,
        const int* __restrict__ src,
        const int* __restrict__ dst,
        unsigned short* __restrict__ Fs16,
        unsigned short* __restrict__ WtB,
        int* __restrict__ slab,
        unsigned short* __restrict__ runoff,
        int n_nodes, int n_edges, int np, int rows_per) {
    __shared__ int cnt[MAXP];        // per-partition count, then exclusive loc
    __shared__ int swt[8];           // per-wave scan totals
    __shared__ __align__(16) int sval[PSCH];
    const int tid = threadIdx.x;
    const int lane = tid & 63;
    const int wv = tid >> 6;
    const int b = blockIdx.x;

    for (int i = tid; i < np; i += SPT) cnt[i] = 0;

    // (A) vectorized Fs16 conversion: one 8-elem chunk per iteration
    {
        const int r0 = b * rows_per;
        const int r1 = min(r0 + rows_per, n_nodes);
        const float4* f4 = (const float4*)feature;
        uint4* o4 = (uint4*)Fs16;
        for (int ch = r0 * 8 + tid; ch < r1 * 8; ch += SPT) {
            const float w = rsqrtf(degree[ch >> 3]);        // 8 chunks per row
            const float4 fa = f4[ch * 2];
            const float4 fb = f4[ch * 2 + 1];
            uint4 o;
            o.x = (unsigned int)f2bf(fa.x * w) | ((unsigned int)f2bf(fa.y * w) << 16);
            o.y = (unsigned int)f2bf(fa.z * w) | ((unsigned int)f2bf(fa.w * w) << 16);
            o.z = (unsigned int)f2bf(fb.x * w) | ((unsigned int)f2bf(fb.y * w) << 16);
            o.w = (unsigned int)f2bf(fb.z * w) | ((unsigned int)f2bf(fb.w * w) << 16);
            o4[ch] = o;
        }
        if (b == 0) {
            if (tid < FEATS) Fs16[(size_t)n_nodes * FEATS + tid] = 0;  // zero row
            for (int idx = tid; idx < FEATS * FEATS; idx += SPT) {
                const int k = idx >> 6, n = idx & 63;
                WtB[n * FEATS + k] = f2bf(Wm[idx]);     // W^T in bf16
            }
        }
    }
    __syncthreads();

    // (B) chunk sort
    const int estart = b * PSCH;
    const int eend = min(estart + PSCH, n_edges);
    const int mb = eend - estart;

    int prk[PEPT];
#pragma unroll
    for (int k = 0; k < PEPT; ++k) {
        const int e = estart + tid + k * SPT;
        prk[k] = 0;
        if (e < eend) {
            const int d = dst[e];
            const int p = d >> 6;                      // 11 bits
            const int r = atomicAdd(&cnt[p], 1);       // LDS atomic (native int)
            prk[k] = p | (r << 11) | ((d & 63) << 23); // r < 2344 (12 bits)
        }
    }
    __syncthreads();

    // exclusive scan of cnt[0..np): 3 partitions/thread, wave shuffle scan,
    // cross-wave prefix via swt — 2 barriers total.
    int my[3];
    int psum = 0;
    const int p0 = tid * 3;
#pragma unroll
    for (int j = 0; j < 3; ++j) {
        const int p = p0 + j;
        my[j] = psum;
        if (p < np) psum += cnt[p];
    }
    int x = psum;                       // wave-inclusive scan of psum
#pragma unroll
    for (int off = 1; off < 64; off <<= 1) {
        const int v = __shfl_up(x, off);
        if (lane >= off) x += v;
    }
    if (lane == 63) swt[wv] = x;
    __syncthreads();
    int wbase = 0;
#pragma unroll
    for (int w = 0; w < 8; ++w) if (w < wv) wbase += swt[w];
    const int tbase = wbase + (x - psum);
#pragma unroll
    for (int j = 0; j < 3; ++j) {
        const int p = p0 + j;
        if (p < np) cnt[p] = tbase + my[j];            // cnt becomes loc
    }
    __syncthreads();

#pragma unroll
    for (int k = 0; k < PEPT; ++k) {
        const int e = estart + tid + k * SPT;
        if (e < eend) {
            const int pr = prk[k];
            const int p = pr & 2047;
            const int r = (pr >> 11) & 4095;
            const int dl = (pr >> 23) & 63;
            sval[cnt[p] + r] = (src[e] & 0x1FFFF) | (dl << 17);
        }
    }
    __syncthreads();

    int* so = slab + estart;
    const int m4 = mb >> 2;                            // estart*4B is 16B-aligned
    int4* so4 = (int4*)so;
    const int4* sv4 = (const int4*)sval;
    for (int i = tid; i < m4; i += SPT) so4[i] = sv4[i];
    for (int i = (m4 << 2) + tid; i < mb; i += SPT) so[i] = sval[i];
    unsigned short* ro = runoff + (size_t)b * (np + 1);
    for (int i = tid; i <= np; i += SPT)
        ro[i] = (unsigned short)((i < np) ? cnt[i] : mb);
}

// ---------------------------------------------------------------------------
// K2 gather_apply5: block = partition p. NO fp32 LDS atomics.
//  (a) per-node 8-aligned bucket offsets from degree (wave-0 shuffle scan),
//  (b) prefill ledges with zero-row index, bucket records (int LDS atomics),
//  (c) register accumulation, 8 edges per wave-load: slot q8 = lane>>3 takes
//      edge j+q8, each lane loads uint4 (8 bf16 cols = full row in 8 lanes);
//      unroll-2 => 2 outstanding 1KB loads/wave; 3-step shfl_xor fold,
//  (d) MFMA epilogue: bf16 A-tile (stride 72), 8x mfma_16x16x32_bf16,
//      out = swinv[n]*(A@W)+b.
// ---------------------------------------------------------------------------
__global__ __launch_bounds__(256) void gather_apply5(
        const int* __restrict__ slab,
        const unsigned short* __restrict__ runoff,
        const float* __restrict__ degree,
        const unsigned short* __restrict__ Fs16,
        const unsigned short* __restrict__ WtB,
        const float* __restrict__ bias,
        float* __restrict__ out,
        int n_nodes, int np, int nbs) {
    __shared__ __align__(16) int ledges[CAPP];                // 10 KB
    __shared__ __align__(16) unsigned short saggb[PSZ * 72];  // 9.2 KB bf16 A-tile
    __shared__ int boffA[PSZ + 1];
    __shared__ int bcnt[PSZ];
    __shared__ int bcur[PSZ];
    __shared__ float swinv[PSZ];

    const int tid = threadIdx.x;
    const int lane = tid & 63;
    const int wv = tid >> 6;
    const int p = blockIdx.x;
    const int n0 = p * PSZ;
    const int nn = min(PSZ, n_nodes - n0);

    if (tid < PSZ) bcur[tid] = 0;
    if (wv == 0) {   // wave-0: swinv + shuffle scan of 8-padded counts
        const float dg = (lane < nn) ? degree[n0 + lane] : 1.0f;
        swinv[lane] = rsqrtf(dg);
        const int c = (lane < nn) ? ((int)(dg + 0.5f) - 1) : 0;
        const int cp = (c + 7) & ~7;
        int x = cp;
#pragma unroll
        for (int off = 1; off < 64; off <<= 1) {
            const int v = __shfl_up(x, off);
            if (lane >= off) x += v;
        }
        if (lane == 0) boffA[0] = 0;
        boffA[lane + 1] = x;
        bcnt[lane] = c;
    }
    __syncthreads();
    const int mpad = boffA[PSZ];

    if (mpad <= CAPP) {
        // (b) prefill pad slots with zero-row index, then bucket
        for (int i = tid; i < mpad; i += 256) ledges[i] = n_nodes;
        __syncthreads();
        for (int rr = tid; rr < nbs; rr += 256) {
            const unsigned short* ro = runoff + (size_t)rr * (np + 1);
            const int st = ro[p];
            const int en = ro[p + 1];
            const int* g = slab + (size_t)rr * PSCH;
            for (int q = st; q < en; ++q) {
                const int rec = g[q];
                const int dl = (rec >> 17) & 63;
                const int pos = boffA[dl] + atomicAdd(&bcur[dl], 1);
                ledges[pos] = rec & 0x1FFFF;
            }
        }
        __syncthreads();

        // (c) 8 edges per wave-load (uint4/lane = 1KB/instr), unroll-2
        const int q8 = lane >> 3;                  // edge slot within group
        const int c8 = lane & 7;                   // 8 cols per lane
        const uint4* FsU4 = (const uint4*)Fs16;    // 8 uint4 per 128B row
        for (int n = wv; n < PSZ; n += 4) {
            const int st = boffA[n];
            const int en8 = boffA[n + 1];
            float a0 = 0.f, a1 = 0.f, a2 = 0.f, a3 = 0.f;
            float a4 = 0.f, a5 = 0.f, a6 = 0.f, a7 = 0.f;
#pragma unroll 2
            for (int j = st; j < en8; j += 8) {
                const int r = ledges[j + q8];
                const uint4 u = FsU4[((size_t)r << 3) + c8];
                a0 += bflo(u.x); a1 += bfhi(u.x);
                a2 += bflo(u.y); a3 += bfhi(u.y);
                a4 += bflo(u.z); a5 += bfhi(u.z);
                a6 += bflo(u.w); a7 += bfhi(u.w);
            }
#define FOLD(v) v += __shfl_xor(v, 8); v += __shfl_xor(v, 16); v += __shfl_xor(v, 32)
            FOLD(a0); FOLD(a1); FOLD(a2); FOLD(a3);
            FOLD(a4); FOLD(a5); FOLD(a6); FOLD(a7);
#undef FOLD
            if (q8 == 0) {   // lanes 0-7 hold cols c8*8 .. c8*8+7
                uint4 o;
                o.x = (unsigned int)f2bf(a0) | ((unsigned int)f2bf(a1) << 16);
                o.y = (unsigned int)f2bf(a2) | ((unsigned int)f2bf(a3) << 16);
                o.z = (unsigned int)f2bf(a4) | ((unsigned int)f2bf(a5) << 16);
                o.w = (unsigned int)f2bf(a6) | ((unsigned int)f2bf(a7) << 16);
                *(uint4*)(saggb + n * 72 + c8 * 8) = o;   // n*144B + c8*16B: aligned
            }
        }
    } else {
        // statistically-unreachable overflow: per-node scan of all runs
        __syncthreads();
        __syncthreads();
        for (int n = wv; n < PSZ; n += 4) {
            float acc = 0.f;
            for (int t = 0; t < nbs; ++t) {
                const unsigned short* ro = runoff + (size_t)t * (np + 1);
                const int gb = t * PSCH;
                const int e0 = ro[p + 1];
                for (int i = ro[p]; i < e0; ++i) {
                    const int rec = slab[gb + i];
                    if (((rec >> 17) & 63) == n) {
                        const unsigned int us =
                            Fs16[((size_t)(rec & 0x1FFFF) << 6) + lane];
                        acc += __uint_as_float(us << 16);
                    }
                }
            }
            saggb[n * 72 + lane] = f2bf(acc);
        }
    }
    __syncthreads();

    // (d) 64x64x64 GEMM: wave wv owns m-tile wv; 4 n-tiles x 2 k-steps = 8 MFMA
    const int col = lane & 15;
    const int quad = lane >> 4;
    floatx4 acc[4] = {};
#pragma unroll
    for (int kt = 0; kt < 2; ++kt) {
        const short8 af = *(const short8*)(saggb + (wv * 16 + col) * 72 + kt * 32 + quad * 8);
#pragma unroll
        for (int nt = 0; nt < 4; ++nt) {
            const short8 bf = *(const short8*)((const short*)WtB + (nt * 16 + col) * FEATS + kt * 32 + quad * 8);
            acc[nt] = __builtin_amdgcn_mfma_f32_16x16x32_bf16(af, bf, acc[nt], 0, 0, 0);
        }
    }
#pragma unroll
    for (int nt = 0; nt < 4; ++nt) {
        const float bv = bias[nt * 16 + col];
#pragma unroll
        for (int r = 0; r < 4; ++r) {
            const int row = wv * 16 + quad * 4 + r;      // D: col=lane&15, row=quad*4+reg
            if (row < nn)
                out[(size_t)(n0 + row) * FEATS + nt * 16 + col] = swinv[row] * acc[nt][r] + bv;
        }
    }
}

static inline size_t align256(size_t x) { return (x + 255) & ~(size_t)255; }

extern "C" void kernel_launch(void* const* d_in, const int* in_sizes, int n_in,
                              void* d_out, int out_size, void* d_ws, size_t ws_size,
                              hipStream_t stream) {
    const float* feature = (const float*)d_in[0];
    const float* degree  = (const float*)d_in[1];
    const int*   src     = (const int*)d_in[2];
    const int*   dst     = (const int*)d_in[3];
    const float* Wm      = (const float*)d_in[4];
    const float* bias    = (const float*)d_in[5];
    float* out = (float*)d_out;

    const int n_nodes = in_sizes[1];
    const int n_edges = in_sizes[2];
    const int np = (n_nodes + PSZ - 1) / PSZ;           // 1172
    const int nbs = (n_edges + PSCH - 1) / PSCH;        // 512
    const int rows_per = (n_nodes + nbs - 1) / nbs;     // 147

    // workspace (~15.7 MB), every byte read is rewritten each launch
    char* ws = (char*)d_ws;
    unsigned short* Fs16 = (unsigned short*)ws; ws += align256(((size_t)n_nodes + 1) * FEATS * 2);
    unsigned short* WtB  = (unsigned short*)ws; ws += align256((size_t)FEATS * FEATS * 2);
    int* slab = (int*)ws;                       ws += align256((size_t)nbs * PSCH * 4);
    unsigned short* runoff = (unsigned short*)ws; ws += align256((size_t)nbs * (np + 1) * 2);

    prep_scatter<<<nbs, SPT, 0, stream>>>(degree, feature, Wm, src, dst,
                                          Fs16, WtB, slab, runoff,
                                          n_nodes, n_edges, np, rows_per);
    gather_apply5<<<np, 256, 0, stream>>>(slab, runoff, degree, Fs16, WtB, bias, out,
                                          n_nodes, np, nbs);
}

// Round 2
// 134.820 us; speedup vs baseline: 1.0115x; 1.0115x over previous
//
#include <hip/hip_runtime.h>

#define FEATS 64
#define PSZ   64            // nodes per partition (= one gather block)
#define MAXP  1280          // >= ceil(75000/64) = 1172
#define PSCH  1172          // edges per chunk; 1172*1024 >= 1.2M
#define SPT   512           // prep_scatter threads per block
#define PEPT  3             // ceil(PSCH/SPT)
#define CAPP  2560          // padded LDS bucket capacity (mean ~1500 w/ pad16)

typedef __attribute__((ext_vector_type(8))) short short8;   // 8 bf16 = 4 VGPRs
typedef __attribute__((ext_vector_type(4))) float floatx4;  // MFMA accumulator

static __device__ __forceinline__ unsigned short f2bf(float f) {
    const unsigned int u = __float_as_uint(f);
    return (unsigned short)((u + 0x7FFFu + ((u >> 16) & 1u)) >> 16);
}
static __device__ __forceinline__ float bflo(unsigned int u) {
    return __uint_as_float(u << 16);            // low bf16 -> fp32
}
static __device__ __forceinline__ float bfhi(unsigned int u) {
    return __uint_as_float(u & 0xFFFF0000u);    // high bf16 -> fp32
}

// ---------------------------------------------------------------------------
// K1 prep_scatter: grid=1024 (4 blocks/CU x 8 waves = full occupancy).
//  (A) vectorized Fs16 = bf16(feature * rsqrt(deg)) — 8 elems/thread;
//  (B) LDS partition-sort of a PSCH-edge chunk; wave-shuffle scan (2 barriers).
// Record = src | dl<<17 ; prk = p | r<<11 | dl<<23  (r < 1172, 12 bits).
// ---------------------------------------------------------------------------
__global__ __launch_bounds__(SPT) void prep_scatter(
        const float* __restrict__ degree,
        const float* __restrict__ feature,
        const float* __restrict__ Wm,
        const int* __restrict__ src,
        const int* __restrict__ dst,
        unsigned short* __restrict__ Fs16,
        unsigned short* __restrict__ WtB,
        int* __restrict__ slab,
        unsigned short* __restrict__ runoff,
        int n_nodes, int n_edges, int np, int rows_per) {
    __shared__ int cnt[MAXP];        // per-partition count, then exclusive loc
    __shared__ int swt[8];           // per-wave scan totals
    __shared__ __align__(16) int sval[PSCH];
    const int tid = threadIdx.x;
    const int lane = tid & 63;
    const int wv = tid >> 6;
    const int b = blockIdx.x;

    for (int i = tid; i < np; i += SPT) cnt[i] = 0;

    // (A) vectorized Fs16 conversion: one 8-elem chunk per iteration
    {
        const int r0 = b * rows_per;
        const int r1 = min(r0 + rows_per, n_nodes);
        const float4* f4 = (const float4*)feature;
        uint4* o4 = (uint4*)Fs16;
        for (int ch = r0 * 8 + tid; ch < r1 * 8; ch += SPT) {
            const float w = rsqrtf(degree[ch >> 3]);        // 8 chunks per row
            const float4 fa = f4[ch * 2];
            const float4 fb = f4[ch * 2 + 1];
            uint4 o;
            o.x = (unsigned int)f2bf(fa.x * w) | ((unsigned int)f2bf(fa.y * w) << 16);
            o.y = (unsigned int)f2bf(fa.z * w) | ((unsigned int)f2bf(fa.w * w) << 16);
            o.z = (unsigned int)f2bf(fb.x * w) | ((unsigned int)f2bf(fb.y * w) << 16);
            o.w = (unsigned int)f2bf(fb.z * w) | ((unsigned int)f2bf(fb.w * w) << 16);
            o4[ch] = o;
        }
        if (b == 0) {
            if (tid < FEATS) Fs16[(size_t)n_nodes * FEATS + tid] = 0;  // zero row
            for (int idx = tid; idx < FEATS * FEATS; idx += SPT) {
                const int k = idx >> 6, n = idx & 63;
                WtB[n * FEATS + k] = f2bf(Wm[idx]);     // W^T in bf16
            }
        }
    }
    __syncthreads();

    // (B) chunk sort
    const int estart = b * PSCH;
    const int eend = min(estart + PSCH, n_edges);
    const int mb = eend - estart;

    int prk[PEPT];
#pragma unroll
    for (int k = 0; k < PEPT; ++k) {
        const int e = estart + tid + k * SPT;
        prk[k] = 0;
        if (e < eend) {
            const int d = dst[e];
            const int p = d >> 6;                      // 11 bits
            const int r = atomicAdd(&cnt[p], 1);       // LDS atomic (native int)
            prk[k] = p | (r << 11) | ((d & 63) << 23); // r < 1172 (12 bits)
        }
    }
    __syncthreads();

    // exclusive scan of cnt[0..np): 3 partitions/thread, wave shuffle scan,
    // cross-wave prefix via swt — 2 barriers total.
    int my[3];
    int psum = 0;
    const int p0 = tid * 3;
#pragma unroll
    for (int j = 0; j < 3; ++j) {
        const int p = p0 + j;
        my[j] = psum;
        if (p < np) psum += cnt[p];
    }
    int x = psum;                       // wave-inclusive scan of psum
#pragma unroll
    for (int off = 1; off < 64; off <<= 1) {
        const int v = __shfl_up(x, off);
        if (lane >= off) x += v;
    }
    if (lane == 63) swt[wv] = x;
    __syncthreads();
    int wbase = 0;
#pragma unroll
    for (int w = 0; w < 8; ++w) if (w < wv) wbase += swt[w];
    const int tbase = wbase + (x - psum);
#pragma unroll
    for (int j = 0; j < 3; ++j) {
        const int p = p0 + j;
        if (p < np) cnt[p] = tbase + my[j];            // cnt becomes loc
    }
    __syncthreads();

#pragma unroll
    for (int k = 0; k < PEPT; ++k) {
        const int e = estart + tid + k * SPT;
        if (e < eend) {
            const int pr = prk[k];
            const int p = pr & 2047;
            const int r = (pr >> 11) & 4095;
            const int dl = (pr >> 23) & 63;
            sval[cnt[p] + r] = (src[e] & 0x1FFFF) | (dl << 17);
        }
    }
    __syncthreads();

    int* so = slab + estart;
    const int m4 = mb >> 2;                            // estart*4B is 16B-aligned
    int4* so4 = (int4*)so;
    const int4* sv4 = (const int4*)sval;
    for (int i = tid; i < m4; i += SPT) so4[i] = sv4[i];
    for (int i = (m4 << 2) + tid; i < mb; i += SPT) so[i] = sval[i];
    unsigned short* ro = runoff + (size_t)b * (np + 1);
    for (int i = tid; i <= np; i += SPT)
        ro[i] = (unsigned short)((i < np) ? cnt[i] : mb);
}

// ---------------------------------------------------------------------------
// K2 gather_apply6: block = partition p, 512 threads (8 waves) for occupancy
//  (4 blocks/CU x 512 = 2048 threads = 32 waves/CU; VGPR capped at 64).
//  (a) per-node 16-aligned bucket offsets (wave-0 shuffle scan),
//  (b) prefill ledges with zero-row index, bucket records — one sort-run per
//      thread (int LDS atomics only),
//  (c) register accumulation, 8 nodes/wave, 16 edges per iter = 2x uint4
//      wave-loads, unroll 2 => 4 x 1KB loads in flight; 3-step shfl_xor fold,
//  (d) MFMA epilogue split across 8 waves: 1 m-tile x 2 n-tiles each.
// ---------------------------------------------------------------------------
__global__ __launch_bounds__(512, 8) void gather_apply6(
        const int* __restrict__ slab,
        const unsigned short* __restrict__ runoff,
        const float* __restrict__ degree,
        const unsigned short* __restrict__ Fs16,
        const unsigned short* __restrict__ WtB,
        const float* __restrict__ bias,
        float* __restrict__ out,
        int n_nodes, int np, int nbs) {
    __shared__ __align__(16) int ledges[CAPP];                // 10 KB
    __shared__ __align__(16) unsigned short saggb[PSZ * 72];  // 9.2 KB bf16 A-tile
    __shared__ int boffA[PSZ + 1];
    __shared__ int bcur[PSZ];
    __shared__ float swinv[PSZ];

    const int tid = threadIdx.x;
    const int lane = tid & 63;
    const int wv = tid >> 6;
    const int p = blockIdx.x;
    const int n0 = p * PSZ;
    const int nn = min(PSZ, n_nodes - n0);

    if (tid < PSZ) bcur[tid] = 0;
    if (wv == 0) {   // wave-0: swinv + shuffle scan of 16-padded counts
        const float dg = (lane < nn) ? degree[n0 + lane] : 1.0f;
        swinv[lane] = rsqrtf(dg);
        const int c = (lane < nn) ? ((int)(dg + 0.5f) - 1) : 0;
        const int cp = (c + 15) & ~15;
        int x = cp;
#pragma unroll
        for (int off = 1; off < 64; off <<= 1) {
            const int v = __shfl_up(x, off);
            if (lane >= off) x += v;
        }
        if (lane == 0) boffA[0] = 0;
        boffA[lane + 1] = x;
    }
    __syncthreads();
    const int mpad = boffA[PSZ];

    if (mpad <= CAPP) {
        // (b) prefill pad slots with zero-row index, then bucket (1 run/thread)
        for (int i = tid; i < mpad; i += SPT) ledges[i] = n_nodes;
        __syncthreads();
        for (int rr = tid; rr < nbs; rr += SPT) {
            const unsigned short* ro = runoff + (size_t)rr * (np + 1);
            const int st = ro[p];
            const int en = ro[p + 1];
            const int* g = slab + (size_t)rr * PSCH;
            for (int q = st; q < en; ++q) {
                const int rec = g[q];
                const int dl = (rec >> 17) & 63;
                const int pos = boffA[dl] + atomicAdd(&bcur[dl], 1);
                ledges[pos] = rec & 0x1FFFF;
            }
        }
        __syncthreads();

        // (c) 16 edges per iteration: 2 x uint4 wave-loads, unroll 2
        const int q8 = lane >> 3;                  // edge slot within group of 8
        const int c8 = lane & 7;                   // 8 cols per lane
        const uint4* FsU4 = (const uint4*)Fs16;    // 8 uint4 per 128B row
        for (int n = wv; n < PSZ; n += 8) {
            const int st = boffA[n];
            const int en16 = boffA[n + 1];
            float a0 = 0.f, a1 = 0.f, a2 = 0.f, a3 = 0.f;
            float a4 = 0.f, a5 = 0.f, a6 = 0.f, a7 = 0.f;
#pragma unroll 2
            for (int j = st; j < en16; j += 16) {
                const int r0 = ledges[j + q8];
                const int r1 = ledges[j + 8 + q8];
                const uint4 u0 = FsU4[((size_t)r0 << 3) + c8];
                const uint4 u1 = FsU4[((size_t)r1 << 3) + c8];
                a0 += bflo(u0.x); a1 += bfhi(u0.x);
                a2 += bflo(u0.y); a3 += bfhi(u0.y);
                a4 += bflo(u0.z); a5 += bfhi(u0.z);
                a6 += bflo(u0.w); a7 += bfhi(u0.w);
                a0 += bflo(u1.x); a1 += bfhi(u1.x);
                a2 += bflo(u1.y); a3 += bfhi(u1.y);
                a4 += bflo(u1.z); a5 += bfhi(u1.z);
                a6 += bflo(u1.w); a7 += bfhi(u1.w);
            }
#define FOLD(v) v += __shfl_xor(v, 8); v += __shfl_xor(v, 16); v += __shfl_xor(v, 32)
            FOLD(a0); FOLD(a1); FOLD(a2); FOLD(a3);
            FOLD(a4); FOLD(a5); FOLD(a6); FOLD(a7);
#undef FOLD
            if (q8 == 0) {   // lanes 0-7 hold cols c8*8 .. c8*8+7
                uint4 o;
                o.x = (unsigned int)f2bf(a0) | ((unsigned int)f2bf(a1) << 16);
                o.y = (unsigned int)f2bf(a2) | ((unsigned int)f2bf(a3) << 16);
                o.z = (unsigned int)f2bf(a4) | ((unsigned int)f2bf(a5) << 16);
                o.w = (unsigned int)f2bf(a6) | ((unsigned int)f2bf(a7) << 16);
                *(uint4*)(saggb + n * 72 + c8 * 8) = o;   // n*144B + c8*16B: aligned
            }
        }
    } else {
        // statistically-unreachable overflow: per-node scan of all runs
        __syncthreads();
        __syncthreads();
        for (int n = wv; n < PSZ; n += 8) {
            float acc = 0.f;
            for (int t = 0; t < nbs; ++t) {
                const unsigned short* ro = runoff + (size_t)t * (np + 1);
                const int gb = t * PSCH;
                const int e0 = ro[p + 1];
                for (int i = ro[p]; i < e0; ++i) {
                    const int rec = slab[gb + i];
                    if (((rec >> 17) & 63) == n) {
                        const unsigned int us =
                            Fs16[((size_t)(rec & 0x1FFFF) << 6) + lane];
                        acc += __uint_as_float(us << 16);
                    }
                }
            }
            saggb[n * 72 + lane] = f2bf(acc);
        }
    }
    __syncthreads();

    // (d) 64x64x64 GEMM over 8 waves: wave wv -> m-tile wv>>1, n-tiles (wv&1)*2+{0,1}
    const int col = lane & 15;
    const int quad = lane >> 4;
    const int mt = wv >> 1;
    const int nh = (wv & 1) << 1;
    floatx4 acc[2] = {};
#pragma unroll
    for (int kt = 0; kt < 2; ++kt) {
        const short8 af = *(const short8*)(saggb + (mt * 16 + col) * 72 + kt * 32 + quad * 8);
#pragma unroll
        for (int t = 0; t < 2; ++t) {
            const int nt = nh + t;
            const short8 bf = *(const short8*)((const short*)WtB + (nt * 16 + col) * FEATS + kt * 32 + quad * 8);
            acc[t] = __builtin_amdgcn_mfma_f32_16x16x32_bf16(af, bf, acc[t], 0, 0, 0);
        }
    }
#pragma unroll
    for (int t = 0; t < 2; ++t) {
        const int nt = nh + t;
        const float bv = bias[nt * 16 + col];
#pragma unroll
        for (int r = 0; r < 4; ++r) {
            const int row = mt * 16 + quad * 4 + r;      // D: col=lane&15, row=quad*4+reg
            if (row < nn)
                out[(size_t)(n0 + row) * FEATS + nt * 16 + col] = swinv[row] * acc[t][r] + bv;
        }
    }
}

static inline size_t align256(size_t x) { return (x + 255) & ~(size_t)255; }

extern "C" void kernel_launch(void* const* d_in, const int* in_sizes, int n_in,
                              void* d_out, int out_size, void* d_ws, size_t ws_size,
                              hipStream_t stream) {
    const float* feature = (const float*)d_in[0];
    const float* degree  = (const float*)d_in[1];
    const int*   src     = (const int*)d_in[2];
    const int*   dst     = (const int*)d_in[3];
    const float* Wm      = (const float*)d_in[4];
    const float* bias    = (const float*)d_in[5];
    float* out = (float*)d_out;

    const int n_nodes = in_sizes[1];
    const int n_edges = in_sizes[2];
    const int np = (n_nodes + PSZ - 1) / PSZ;           // 1172
    const int nbs = (n_edges + PSCH - 1) / PSCH;        // 1024
    const int rows_per = (n_nodes + nbs - 1) / nbs;     // 74

    // workspace (~16.5 MB), every byte read is rewritten each launch
    char* ws = (char*)d_ws;
    unsigned short* Fs16 = (unsigned short*)ws; ws += align256(((size_t)n_nodes + 1) * FEATS * 2);
    unsigned short* WtB  = (unsigned short*)ws; ws += align256((size_t)FEATS * FEATS * 2);
    int* slab = (int*)ws;                       ws += align256((size_t)nbs * PSCH * 4);
    unsigned short* runoff = (unsigned short*)ws; ws += align256((size_t)nbs * (np + 1) * 2);

    prep_scatter<<<nbs, SPT, 0, stream>>>(degree, feature, Wm, src, dst,
                                          Fs16, WtB, slab, runoff,
                                          n_nodes, n_edges, np, rows_per);
    gather_apply6<<<np, SPT, 0, stream>>>(slab, runoff, degree, Fs16, WtB, bias, out,
                                          n_nodes, np, nbs);
}

// Round 3
// 133.100 us; speedup vs baseline: 1.0246x; 1.0129x over previous
//
#include <hip/hip_runtime.h>

#define FEATS 64
#define PSZ   64            // nodes per partition (= one gather block)
#define MAXP  1280          // >= ceil(75000/64) = 1172
#define PSCH  4688          // edges per chunk; 4688*256 >= 1.2M
#define SPT   512           // sort/gather threads per block
#define PEPT  10            // ceil(PSCH/SPT)
#define CAPP  2560          // padded LDS bucket capacity (mean ~1560, >30 sigma)

typedef __attribute__((ext_vector_type(8))) short short8;   // 8 bf16 = 4 VGPRs
typedef __attribute__((ext_vector_type(4))) float floatx4;  // MFMA accumulator

static __device__ __forceinline__ unsigned short f2bf(float f) {
    const unsigned int u = __float_as_uint(f);
    return (unsigned short)((u + 0x7FFFu + ((u >> 16) & 1u)) >> 16);
}
static __device__ __forceinline__ float bflo(unsigned int u) {
    return __uint_as_float(u << 16);            // low bf16 -> fp32
}
static __device__ __forceinline__ float bfhi(unsigned int u) {
    return __uint_as_float(u & 0xFFFF0000u);    // high bf16 -> fp32
}

// ---------------------------------------------------------------------------
// K0 convert_k: pure streaming, grid 2048x256 (full machine).
//  Fs16 = bf16(feature * rsqrt(degree[row])), zero pad-row, WtB = W^T bf16.
// ---------------------------------------------------------------------------
__global__ __launch_bounds__(256) void convert_k(
        const float* __restrict__ degree,
        const float* __restrict__ feature,
        const float* __restrict__ Wm,
        unsigned short* __restrict__ Fs16,
        unsigned short* __restrict__ WtB,
        int n_nodes) {
    const int gtid = blockIdx.x * 256 + threadIdx.x;
    const int total = n_nodes * 8;                  // 8-elem chunks
    const float4* f4 = (const float4*)feature;
    uint4* o4 = (uint4*)Fs16;
    for (int ch = gtid; ch < total; ch += 2048 * 256) {
        const float w = rsqrtf(degree[ch >> 3]);
        const float4 fa = f4[ch * 2];
        const float4 fb = f4[ch * 2 + 1];
        uint4 o;
        o.x = (unsigned int)f2bf(fa.x * w) | ((unsigned int)f2bf(fa.y * w) << 16);
        o.y = (unsigned int)f2bf(fa.z * w) | ((unsigned int)f2bf(fa.w * w) << 16);
        o.z = (unsigned int)f2bf(fb.x * w) | ((unsigned int)f2bf(fb.y * w) << 16);
        o.w = (unsigned int)f2bf(fb.z * w) | ((unsigned int)f2bf(fb.w * w) << 16);
        o4[ch] = o;
    }
    if (blockIdx.x == 0) {
        if (threadIdx.x < FEATS) Fs16[(size_t)n_nodes * FEATS + threadIdx.x] = 0;
        for (int idx = threadIdx.x; idx < FEATS * FEATS; idx += 256) {
            const int k = idx >> 6, n = idx & 63;
            WtB[n * FEATS + k] = f2bf(Wm[idx]);     // W^T in bf16
        }
    }
}

// ---------------------------------------------------------------------------
// K1 prep_sort: grid=256 chunks x 512 thr. LDS partition-sort of PSCH edges.
//  Long runs (~4.6 records) shrink K2's scattered reads 4x. runoffT is
//  TRANSPOSED [partition][chunk] so K2 reads contiguous rows.
// prk = p | r<<11 | dl<<24 (r < 4688: 13 bits). Record = src | dl<<17.
// ---------------------------------------------------------------------------
__global__ __launch_bounds__(SPT) void prep_sort(
        const int* __restrict__ src,
        const int* __restrict__ dst,
        int* __restrict__ slab,
        unsigned short* __restrict__ runoffT,
        int n_edges, int np, int nbs) {
    __shared__ int cnt[MAXP];        // per-partition count, then exclusive loc
    __shared__ int swt[8];           // per-wave scan totals
    __shared__ __align__(16) int sval[PSCH];
    const int tid = threadIdx.x;
    const int lane = tid & 63;
    const int wv = tid >> 6;
    const int b = blockIdx.x;

    for (int i = tid; i < np; i += SPT) cnt[i] = 0;
    __syncthreads();

    const int estart = b * PSCH;
    const int eend = min(estart + PSCH, n_edges);
    const int mb = eend - estart;

    int prk[PEPT];
#pragma unroll
    for (int k = 0; k < PEPT; ++k) {
        const int e = estart + tid + k * SPT;
        prk[k] = 0;
        if (e < eend) {
            const int d = dst[e];
            const int p = d >> 6;                      // 11 bits
            const int r = atomicAdd(&cnt[p], 1);       // LDS atomic (native int)
            prk[k] = p | (r << 11) | ((d & 63) << 24); // r < 4688 (13 bits)
        }
    }
    __syncthreads();

    // exclusive scan of cnt[0..np): 3 partitions/thread, wave shuffle scan,
    // cross-wave prefix via swt — 2 barriers total.
    int my[3];
    int psum = 0;
    const int p0 = tid * 3;
#pragma unroll
    for (int j = 0; j < 3; ++j) {
        const int p = p0 + j;
        my[j] = psum;
        if (p < np) psum += cnt[p];
    }
    int x = psum;                       // wave-inclusive scan of psum
#pragma unroll
    for (int off = 1; off < 64; off <<= 1) {
        const int v = __shfl_up(x, off);
        if (lane >= off) x += v;
    }
    if (lane == 63) swt[wv] = x;
    __syncthreads();
    int wbase = 0;
#pragma unroll
    for (int w = 0; w < 8; ++w) if (w < wv) wbase += swt[w];
    const int tbase = wbase + (x - psum);
#pragma unroll
    for (int j = 0; j < 3; ++j) {
        const int p = p0 + j;
        if (p < np) cnt[p] = tbase + my[j];            // cnt becomes loc
    }
    __syncthreads();

#pragma unroll
    for (int k = 0; k < PEPT; ++k) {
        const int e = estart + tid + k * SPT;
        if (e < eend) {
            const int pr = prk[k];
            const int p = pr & 2047;
            const int r = (pr >> 11) & 8191;
            const int dl = (pr >> 24) & 63;
            sval[cnt[p] + r] = (src[e] & 0x1FFFF) | (dl << 17);
        }
    }
    __syncthreads();

    int* so = slab + estart;
    const int m4 = mb >> 2;                            // estart*4B is 16B-aligned
    int4* so4 = (int4*)so;
    const int4* sv4 = (const int4*)sval;
    for (int i = tid; i < m4; i += SPT) so4[i] = sv4[i];
    for (int i = (m4 << 2) + tid; i < mb; i += SPT) so[i] = sval[i];
    // transposed run-offset write: runoffT[p][b], scattered 2B stores into a
    // 600 KB L2-resident array (write side absorbs the scatter, read side is
    // contiguous in K2)
    for (int i = tid; i <= np; i += SPT)
        runoffT[(size_t)i * nbs + b] = (unsigned short)((i < np) ? cnt[i] : mb);
}

// ---------------------------------------------------------------------------
// K2 gather_apply7: block = partition (XCD-chunk-swizzled), 512 threads.
//  (a) per-node 16-aligned bucket offsets (wave-0 shuffle scan),
//  (b) bucket: contiguous runoffT rows p,p+1 (1 KB) + 256 short slab
//      segments (~18 B each, neighbors share lines -> L2 via swizzle),
//      2 threads per run, int LDS atomics only,
//  (c) register accumulation: 16 edges/iter = 2x uint4 wave-loads, unroll 2
//      => 4 x 1KB loads in flight; 3-step shfl_xor fold,
//  (d) MFMA epilogue split across 8 waves: 1 m-tile x 2 n-tiles each.
// ---------------------------------------------------------------------------
__global__ __launch_bounds__(512, 8) void gather_apply7(
        const int* __restrict__ slab,
        const unsigned short* __restrict__ runoffT,
        const float* __restrict__ degree,
        const unsigned short* __restrict__ Fs16,
        const unsigned short* __restrict__ WtB,
        const float* __restrict__ bias,
        float* __restrict__ out,
        int n_nodes, int np, int nbs) {
    __shared__ __align__(16) int ledges[CAPP];                // 10 KB
    __shared__ __align__(16) unsigned short saggb[PSZ * 72];  // 9.2 KB bf16 A-tile
    __shared__ int boffA[PSZ + 1];
    __shared__ int bcur[PSZ];
    __shared__ float swinv[PSZ];

    const int tid = threadIdx.x;
    const int lane = tid & 63;
    const int wv = tid >> 6;

    // bijective XCD-chunked swizzle (8 XCDs): consecutive p on same XCD
    int p;
    {
        const int bid = blockIdx.x;
        const int q = np >> 3, r = np & 7;
        const int xcd = bid & 7, idx = bid >> 3;
        p = ((xcd < r) ? xcd * (q + 1) : r * (q + 1) + (xcd - r) * q) + idx;
    }
    const int n0 = p * PSZ;
    const int nn = min(PSZ, n_nodes - n0);

    if (tid < PSZ) bcur[tid] = 0;
    if (wv == 0) {   // wave-0: swinv + shuffle scan of 16-padded counts
        const float dg = (lane < nn) ? degree[n0 + lane] : 1.0f;
        swinv[lane] = rsqrtf(dg);
        const int c = (lane < nn) ? ((int)(dg + 0.5f) - 1) : 0;
        const int cp = (c + 15) & ~15;
        int x = cp;
#pragma unroll
        for (int off = 1; off < 64; off <<= 1) {
            const int v = __shfl_up(x, off);
            if (lane >= off) x += v;
        }
        if (lane == 0) boffA[0] = 0;
        boffA[lane + 1] = x;
    }
    __syncthreads();
    const int mpad = boffA[PSZ];

    if (mpad <= CAPP) {
        // (b) prefill pad slots with zero-row index, then bucket (2 thr/run)
        for (int i = tid; i < mpad; i += SPT) ledges[i] = n_nodes;
        __syncthreads();
        for (int t = tid; t < nbs * 2; t += SPT) {
            const int rr = t >> 1, sub = t & 1;
            const int st = runoffT[(size_t)p * nbs + rr];
            const int en = runoffT[(size_t)(p + 1) * nbs + rr];
            const int* g = slab + (size_t)rr * PSCH;
            for (int q = st + sub; q < en; q += 2) {
                const int rec = g[q];
                const int dl = (rec >> 17) & 63;
                const int pos = boffA[dl] + atomicAdd(&bcur[dl], 1);
                ledges[pos] = rec & 0x1FFFF;
            }
        }
        __syncthreads();

        // (c) 16 edges per iteration: 2 x uint4 wave-loads, unroll 2
        const int q8 = lane >> 3;                  // edge slot within group of 8
        const int c8 = lane & 7;                   // 8 cols per lane
        const uint4* FsU4 = (const uint4*)Fs16;    // 8 uint4 per 128B row
        for (int n = wv; n < PSZ; n += 8) {
            const int st = boffA[n];
            const int en16 = boffA[n + 1];
            float a0 = 0.f, a1 = 0.f, a2 = 0.f, a3 = 0.f;
            float a4 = 0.f, a5 = 0.f, a6 = 0.f, a7 = 0.f;
#pragma unroll 2
            for (int j = st; j < en16; j += 16) {
                const int r0 = ledges[j + q8];
                const int r1 = ledges[j + 8 + q8];
                const uint4 u0 = FsU4[((size_t)r0 << 3) + c8];
                const uint4 u1 = FsU4[((size_t)r1 << 3) + c8];
                a0 += bflo(u0.x); a1 += bfhi(u0.x);
                a2 += bflo(u0.y); a3 += bfhi(u0.y);
                a4 += bflo(u0.z); a5 += bfhi(u0.z);
                a6 += bflo(u0.w); a7 += bfhi(u0.w);
                a0 += bflo(u1.x); a1 += bfhi(u1.x);
                a2 += bflo(u1.y); a3 += bfhi(u1.y);
                a4 += bflo(u1.z); a5 += bfhi(u1.z);
                a6 += bflo(u1.w); a7 += bfhi(u1.w);
            }
#define FOLD(v) v += __shfl_xor(v, 8); v += __shfl_xor(v, 16); v += __shfl_xor(v, 32)
            FOLD(a0); FOLD(a1); FOLD(a2); FOLD(a3);
            FOLD(a4); FOLD(a5); FOLD(a6); FOLD(a7);
#undef FOLD
            if (q8 == 0) {   // lanes 0-7 hold cols c8*8 .. c8*8+7
                uint4 o;
                o.x = (unsigned int)f2bf(a0) | ((unsigned int)f2bf(a1) << 16);
                o.y = (unsigned int)f2bf(a2) | ((unsigned int)f2bf(a3) << 16);
                o.z = (unsigned int)f2bf(a4) | ((unsigned int)f2bf(a5) << 16);
                o.w = (unsigned int)f2bf(a6) | ((unsigned int)f2bf(a7) << 16);
                *(uint4*)(saggb + n * 72 + c8 * 8) = o;   // n*144B + c8*16B: aligned
            }
        }
    } else {
        // statistically-unreachable overflow: per-node scan of all runs
        __syncthreads();
        __syncthreads();
        for (int n = wv; n < PSZ; n += 8) {
            float acc = 0.f;
            for (int t = 0; t < nbs; ++t) {
                const int st = runoffT[(size_t)p * nbs + t];
                const int en = runoffT[(size_t)(p + 1) * nbs + t];
                const int gb = t * PSCH;
                for (int i = st; i < en; ++i) {
                    const int rec = slab[gb + i];
                    if (((rec >> 17) & 63) == n) {
                        const unsigned int us =
                            Fs16[((size_t)(rec & 0x1FFFF) << 6) + lane];
                        acc += __uint_as_float(us << 16);
                    }
                }
            }
            saggb[n * 72 + lane] = f2bf(acc);
        }
    }
    __syncthreads();

    // (d) 64x64x64 GEMM over 8 waves: wave wv -> m-tile wv>>1, n-tiles (wv&1)*2+{0,1}
    const int col = lane & 15;
    const int quad = lane >> 4;
    const int mt = wv >> 1;
    const int nh = (wv & 1) << 1;
    floatx4 acc[2] = {};
#pragma unroll
    for (int kt = 0; kt < 2; ++kt) {
        const short8 af = *(const short8*)(saggb + (mt * 16 + col) * 72 + kt * 32 + quad * 8);
#pragma unroll
        for (int t = 0; t < 2; ++t) {
            const int nt = nh + t;
            const short8 bf = *(const short8*)((const short*)WtB + (nt * 16 + col) * FEATS + kt * 32 + quad * 8);
            acc[t] = __builtin_amdgcn_mfma_f32_16x16x32_bf16(af, bf, acc[t], 0, 0, 0);
        }
    }
#pragma unroll
    for (int t = 0; t < 2; ++t) {
        const int nt = nh + t;
        const float bv = bias[nt * 16 + col];
#pragma unroll
        for (int r = 0; r < 4; ++r) {
            const int row = mt * 16 + quad * 4 + r;      // D: col=lane&15, row=quad*4+reg
            if (row < nn)
                out[(size_t)(n0 + row) * FEATS + nt * 16 + col] = swinv[row] * acc[t][r] + bv;
        }
    }
}

static inline size_t align256(size_t x) { return (x + 255) & ~(size_t)255; }

extern "C" void kernel_launch(void* const* d_in, const int* in_sizes, int n_in,
                              void* d_out, int out_size, void* d_ws, size_t ws_size,
                              hipStream_t stream) {
    const float* feature = (const float*)d_in[0];
    const float* degree  = (const float*)d_in[1];
    const int*   src     = (const int*)d_in[2];
    const int*   dst     = (const int*)d_in[3];
    const float* Wm      = (const float*)d_in[4];
    const float* bias    = (const float*)d_in[5];
    float* out = (float*)d_out;

    const int n_nodes = in_sizes[1];
    const int n_edges = in_sizes[2];
    const int np = (n_nodes + PSZ - 1) / PSZ;           // 1172
    const int nbs = (n_edges + PSCH - 1) / PSCH;        // 256

    // workspace (~15.3 MB), every byte read is rewritten each launch
    char* ws = (char*)d_ws;
    unsigned short* Fs16 = (unsigned short*)ws; ws += align256(((size_t)n_nodes + 1) * FEATS * 2);
    unsigned short* WtB  = (unsigned short*)ws; ws += align256((size_t)FEATS * FEATS * 2);
    int* slab = (int*)ws;                       ws += align256((size_t)nbs * PSCH * 4);
    unsigned short* runoffT = (unsigned short*)ws; ws += align256((size_t)(np + 1) * nbs * 2);

    convert_k<<<2048, 256, 0, stream>>>(degree, feature, Wm, Fs16, WtB, n_nodes);
    prep_sort<<<nbs, SPT, 0, stream>>>(src, dst, slab, runoffT, n_edges, np, nbs);
    gather_apply7<<<np, SPT, 0, stream>>>(slab, runoffT, degree, Fs16, WtB, bias, out,
                                          n_nodes, np, nbs);
}